// Round 2
// baseline (3586.253 us; speedup 1.0000x reference)
//
#include <hip/hip_runtime.h>
#include <math.h>

#define HWS 4096
#define BATCH 16
#define WDIM 64

// ---------------- LayerNorm over channel dim ----------------
__global__ void ln_kernel(const float* __restrict__ x, const float* __restrict__ w,
                          const float* __restrict__ bia, float* __restrict__ out, int CH) {
  int b = blockIdx.y;
  int p = blockIdx.x * blockDim.x + threadIdx.x;
  const float* xp = x + (size_t)b * CH * HWS + p;
  float s = 0.f, s2 = 0.f;
  for (int c = 0; c < CH; ++c) { float v = xp[(size_t)c * HWS]; s += v; s2 = fmaf(v, v, s2); }
  float mu = s / CH;
  float var = s2 / CH - mu * mu;
  float inv = rsqrtf(var + 1e-5f);
  float* op = out + (size_t)b * CH * HWS + p;
  for (int c = 0; c < CH; ++c) {
    op[(size_t)c * HWS] = (xp[(size_t)c * HWS] - mu) * inv * w[c] + bia[c];
  }
}

// ---------------- conv1x1 = GEMM: out[b,o,p] = sum_i W[o,i] * X[b,i,p] ----------------
// grid (HW/128, O/32, NB), block 256. 32(o) x 128(p) tile, 4x4 per thread.
template<bool RES>
__launch_bounds__(256)
__global__ void conv1x1_kernel(const float* __restrict__ X, const float* __restrict__ W,
                               const float* __restrict__ res, float* __restrict__ out,
                               int I, int O) {
  __shared__ float Ws[16][36];
  __shared__ float Xs[16][132];
  int b = blockIdx.z;
  int o0 = blockIdx.y * 32;
  int p0 = blockIdx.x * 128;
  int tid = threadIdx.x;
  int tx = tid & 31;   // pixel tile (x4)
  int ty = tid >> 5;   // out-ch tile (x4)
  const float* Xb = X + (size_t)b * I * HWS;
  float acc[4][4] = {};
  for (int i0 = 0; i0 < I; i0 += 16) {
    {
      int o = o0 + (tid & 31);
      int ii = (tid >> 5) * 2;
      float2 wv = *reinterpret_cast<const float2*>(&W[(size_t)o * I + i0 + ii]);
      Ws[ii][tid & 31] = wv.x;
      Ws[ii + 1][tid & 31] = wv.y;
    }
    {
      int s = tid;
      #pragma unroll
      for (int r = 0; r < 2; ++r, s += 256) {
        int row = s >> 5, c4 = (s & 31) * 4;
        float4 xv = *reinterpret_cast<const float4*>(&Xb[(size_t)(i0 + row) * HWS + p0 + c4]);
        *reinterpret_cast<float4*>(&Xs[row][c4]) = xv;
      }
    }
    __syncthreads();
    #pragma unroll
    for (int kk = 0; kk < 16; ++kk) {
      float4 av = *reinterpret_cast<const float4*>(&Ws[kk][ty * 4]);
      float4 bv = *reinterpret_cast<const float4*>(&Xs[kk][tx * 4]);
      float a[4] = {av.x, av.y, av.z, av.w};
      float bb[4] = {bv.x, bv.y, bv.z, bv.w};
      #pragma unroll
      for (int i = 0; i < 4; ++i)
        #pragma unroll
        for (int j = 0; j < 4; ++j)
          acc[i][j] = fmaf(a[i], bb[j], acc[i][j]);
    }
    __syncthreads();
  }
  #pragma unroll
  for (int i = 0; i < 4; ++i) {
    int o = o0 + ty * 4 + i;
    size_t base = ((size_t)b * O + o) * HWS + p0 + tx * 4;
    float4 rv = make_float4(acc[i][0], acc[i][1], acc[i][2], acc[i][3]);
    if (RES) {
      float4 r2 = *reinterpret_cast<const float4*>(&res[base]);
      rv.x += r2.x; rv.y += r2.y; rv.z += r2.z; rv.w += r2.w;
    }
    *reinterpret_cast<float4*>(&out[base]) = rv;
  }
}

// ---------------- depthwise 3x3, zero pad ----------------
__global__ void dw3_kernel(const float* __restrict__ in, const float* __restrict__ w,
                           float* __restrict__ out, int CH) {
  int bc = blockIdx.y;
  int ch = bc % CH;
  int p = blockIdx.x * blockDim.x + threadIdx.x;
  int y = p >> 6, x = p & 63;
  const float* ip = in + (size_t)bc * HWS;
  const float* wp = w + ch * 9;
  float s = 0.f;
  #pragma unroll
  for (int ky = 0; ky < 3; ++ky) {
    int yy = y + ky - 1;
    if (yy < 0 || yy >= WDIM) continue;
    #pragma unroll
    for (int kx = 0; kx < 3; ++kx) {
      int xx = x + kx - 1;
      if (xx < 0 || xx >= WDIM) continue;
      s = fmaf(wp[ky * 3 + kx], ip[yy * WDIM + xx], s);
    }
  }
  out[(size_t)bc * HWS + p] = s;
}

// ---------------- row L2 norm over HW (per b,channel) ----------------
__global__ void rownorm_kernel(const float* __restrict__ src, float* __restrict__ dst,
                               int CH, int ROWMUL) {
  int bc = blockIdx.x;
  int b = bc / CH, ch = bc % CH;
  const float* p = src + ((size_t)b * ROWMUL + ch) * HWS;
  float s = 0.f;
  for (int i = threadIdx.x; i < HWS; i += 256) { float v = p[i]; s = fmaf(v, v, s); }
  #pragma unroll
  for (int off = 32; off > 0; off >>= 1) s += __shfl_down(s, off, 64);
  __shared__ float red[4];
  int lane = threadIdx.x & 63, wv = threadIdx.x >> 6;
  if (lane == 0) red[wv] = s;
  __syncthreads();
  if (threadIdx.x == 0) {
    float t = red[0] + red[1] + red[2] + red[3];
    dst[bc] = fmaxf(sqrtf(t), 1e-12f);
  }
}

// ---------------- QK^T split-K partials: raw dots (no norms yet) ----------------
// grid (8 splits, NB*HEADS), block 128
template<int c>
__global__ void qk_partial_kernel(const float* __restrict__ qb, const float* __restrict__ kvb,
                                  float* __restrict__ part, int CH) {
  constexpr int TC = c / 4;
  int split = blockIdx.x, bh = blockIdx.y;
  int b = bh >> 3, h = bh & 7;
  const float* qrow = qb + ((size_t)b * CH + h * c) * HWS;
  const float* krow = kvb + ((size_t)b * 2 * CH + h * c) * HWS;
  __shared__ float qs[c][65];
  __shared__ float ks[c][65];
  int tid = threadIdx.x;
  int tc = tid / TC, td = tid % TC;
  bool active = tid < TC * TC;
  float acc[4][4] = {};
  for (int s = 0; s < 8; ++s) {
    int n0 = split * 512 + s * 64;
    for (int e = tid; e < c * 64; e += 128) {
      int r = e >> 6, col = e & 63;
      qs[r][col] = qrow[(size_t)r * HWS + n0 + col];
      ks[r][col] = krow[(size_t)r * HWS + n0 + col];
    }
    __syncthreads();
    if (active) {
      for (int kk = 0; kk < 64; ++kk) {
        float a[4], bb[4];
        #pragma unroll
        for (int i = 0; i < 4; ++i) { a[i] = qs[tc * 4 + i][kk]; bb[i] = ks[td * 4 + i][kk]; }
        #pragma unroll
        for (int i = 0; i < 4; ++i)
          #pragma unroll
          for (int j = 0; j < 4; ++j)
            acc[i][j] = fmaf(a[i], bb[j], acc[i][j]);
      }
    }
    __syncthreads();
  }
  if (active) {
    #pragma unroll
    for (int i = 0; i < 4; ++i)
      #pragma unroll
      for (int j = 0; j < 4; ++j)
        part[(((size_t)bh * 8 + split) * 36 + tc * 4 + i) * 36 + td * 4 + j] = acc[i][j];
  }
}

// ---------------- reduce partials, apply norms+temp, softmax over d ----------------
// grid (NB*HEADS), block 64
template<int c>
__global__ void attn_softmax_kernel(const float* __restrict__ part, const float* __restrict__ nq,
                                    const float* __restrict__ nk, const float* __restrict__ temp,
                                    float* __restrict__ attnw, int CH) {
  int bh = blockIdx.x;
  int b = bh >> 3, h = bh & 7;
  __shared__ float Ss[c][c];
  int tid = threadIdx.x;
  for (int e = tid; e < c * c; e += 64) {
    int r = e / c, d = e % c;
    float s = 0.f;
    for (int sp = 0; sp < 8; ++sp)
      s += part[(((size_t)bh * 8 + sp) * 36 + r) * 36 + d];
    s = s / (nq[b * CH + h * c + r] * nk[b * CH + h * c + d]) * temp[h];
    Ss[r][d] = s;
  }
  __syncthreads();
  if (tid < c) {
    int r = tid;
    float m = -1e30f;
    for (int d = 0; d < c; ++d) m = fmaxf(m, Ss[r][d]);
    float sum = 0.f;
    for (int d = 0; d < c; ++d) { float e = expf(Ss[r][d] - m); sum += e; Ss[r][d] = e; }
    float inv = 1.f / sum;
    for (int d = 0; d < c; ++d)
      attnw[((size_t)bh * 36 + r) * 36 + d] = Ss[r][d] * inv;
  }
}

// ---------------- PV: out[b, h*c+ci, p] = sum_d attn[ci,d] * v[d,p] ----------------
// grid (HW/256, HEADS, NB), block 256
template<int c>
__global__ void pv_kernel(const float* __restrict__ attnw, const float* __restrict__ kvb,
                          float* __restrict__ out, int CH) {
  __shared__ float As[c * c];
  int p = blockIdx.x * blockDim.x + threadIdx.x;
  int h = blockIdx.y, b = blockIdx.z;
  int bh = b * 8 + h;
  for (int e = threadIdx.x; e < c * c; e += 256)
    As[e] = attnw[((size_t)bh * 36 + e / c) * 36 + e % c];
  __syncthreads();
  const float* vb = kvb + ((size_t)b * 2 * CH + CH + h * c) * HWS + p;
  float vr[c];
  #pragma unroll
  for (int d = 0; d < c; ++d) vr[d] = vb[(size_t)d * HWS];
  float* ob = out + ((size_t)b * CH + h * c) * HWS + p;
  #pragma unroll
  for (int ci = 0; ci < c; ++ci) {
    float s = 0.f;
    #pragma unroll
    for (int d = 0; d < c; ++d) s = fmaf(As[ci * c + d], vr[d], s);
    ob[(size_t)ci * HWS] = s;
  }
}

// ---------------- fused dwconv3 + GELU gate: out[ch] = gelu(dw(ch)) * dw(ch+C2) ----------------
// in has 2*C2 channels; grid (HW/256, NB*C2), block 256
__global__ void dwgate_kernel(const float* __restrict__ in, const float* __restrict__ w,
                              float* __restrict__ out, int C2) {
  int bc = blockIdx.y;
  int b = bc / C2, ch = bc % C2;
  int p = blockIdx.x * blockDim.x + threadIdx.x;
  int y = p >> 6, x = p & 63;
  const float* i1 = in + ((size_t)b * 2 * C2 + ch) * HWS;
  const float* i2 = i1 + (size_t)C2 * HWS;
  const float* w1 = w + ch * 9;
  const float* w2 = w + (ch + C2) * 9;
  float s1 = 0.f, s2 = 0.f;
  #pragma unroll
  for (int ky = 0; ky < 3; ++ky) {
    int yy = y + ky - 1;
    if (yy < 0 || yy >= WDIM) continue;
    #pragma unroll
    for (int kx = 0; kx < 3; ++kx) {
      int xx = x + kx - 1;
      if (xx < 0 || xx >= WDIM) continue;
      float w1v = w1[ky * 3 + kx], w2v = w2[ky * 3 + kx];
      s1 = fmaf(w1v, i1[yy * WDIM + xx], s1);
      s2 = fmaf(w2v, i2[yy * WDIM + xx], s2);
    }
  }
  float g = 0.5f * s1 * (1.f + erff(s1 * 0.70710678118654752f));
  out[((size_t)b * C2 + ch) * HWS + p] = g * s2;
}

// ---------------- one transformer branch, one batch chunk of NB images ----------------
// Workspace layout: 6 regions of U floats each (U sized for CH=288 at chunk NB),
// then small attention buffers.
// Attention: U0=LN, U1=conv_q, U2=dw_q, U3..U4=conv_kv, U0..U1=dw_kv, U3=pv_out.
// FFN:       U5=LN, U0..U3=conv_in, U4..U5=dwgate, out=conv_out+res.
template<int c>
static void run_branch(const float* xin, const float* fmap,
                       const float* n1w, const float* n1b, const float* n2w, const float* n2b,
                       const float* temp, const float* qw, const float* qdw,
                       const float* kvw, const float* kvdw, const float* pw,
                       const float* fin, const float* fdw, const float* fout,
                       float* xout, float* ws, size_t U, int NB, hipStream_t stream) {
  const int CH = 8 * c;
  float* U0 = ws;
  float* U1 = ws + U;
  float* U2 = ws + 2 * U;
  float* U3 = ws + 3 * U;
  float* U5 = ws + 5 * U;
  float* part  = ws + 6 * U;                    // NB*82944
  float* attnw = part + (size_t)NB * 82944;     // NB*10368
  float* nq    = attnw + (size_t)NB * 10368;    // NB*288
  float* nk    = nq + (size_t)NB * 288;         // NB*288

  dim3 blk(256);
  // ---- attention block ----
  ln_kernel<<<dim3(16, NB), blk, 0, stream>>>(xin, n1w, n1b, U0, CH);
  conv1x1_kernel<false><<<dim3(32, CH / 32, NB), blk, 0, stream>>>(U0, qw, nullptr, U1, CH, CH);
  dw3_kernel<<<dim3(16, NB * CH), blk, 0, stream>>>(U1, qdw, U2, CH);
  conv1x1_kernel<false><<<dim3(32, 2 * CH / 32, NB), blk, 0, stream>>>(fmap, kvw, nullptr, U3, CH, 2 * CH);
  dw3_kernel<<<dim3(16, NB * 2 * CH), blk, 0, stream>>>(U3, kvdw, U0, 2 * CH);
  rownorm_kernel<<<dim3(NB * CH), blk, 0, stream>>>(U2, nq, CH, CH);
  rownorm_kernel<<<dim3(NB * CH), blk, 0, stream>>>(U0, nk, CH, 2 * CH);
  qk_partial_kernel<c><<<dim3(8, NB * 8), dim3(128), 0, stream>>>(U2, U0, part, CH);
  attn_softmax_kernel<c><<<dim3(NB * 8), dim3(64), 0, stream>>>(part, nq, nk, temp, attnw, CH);
  pv_kernel<c><<<dim3(16, 8, NB), blk, 0, stream>>>(attnw, U0, U3, CH);
  conv1x1_kernel<true><<<dim3(32, CH / 32, NB), blk, 0, stream>>>(U3, pw, xin, xout, CH, CH);
  // ---- FFN block ----
  ln_kernel<<<dim3(16, NB), blk, 0, stream>>>(xout, n2w, n2b, U5, CH);
  conv1x1_kernel<false><<<dim3(32, 4 * CH / 32, NB), blk, 0, stream>>>(U5, fin, nullptr, U0, CH, 4 * CH);
  dwgate_kernel<<<dim3(16, NB * 2 * CH), blk, 0, stream>>>(U0, fdw, ws + 4 * U, 2 * CH);
  conv1x1_kernel<true><<<dim3(32, CH / 32, NB), blk, 0, stream>>>(ws + 4 * U, fout, xout, xout, 2 * CH, CH);
}

extern "C" void kernel_launch(void* const* d_in, const int* in_sizes, int n_in,
                              void* d_out, int out_size, void* d_ws, size_t ws_size,
                              hipStream_t stream) {
  const float* q_L    = (const float*)d_in[0];
  const float* q_H    = (const float*)d_in[1];
  const float* fuse_L = (const float*)d_in[2];
  const float* fuse_H = (const float*)d_in[3];
  const float* n1_w = (const float*)d_in[4];
  const float* n1_b = (const float*)d_in[5];
  const float* n2_w = (const float*)d_in[6];
  const float* n2_b = (const float*)d_in[7];
  const float* n3_w = (const float*)d_in[8];
  const float* n3_b = (const float*)d_in[9];
  const float* n4_w = (const float*)d_in[10];
  const float* n4_b = (const float*)d_in[11];
  const float* a1_temp = (const float*)d_in[12];
  const float* a1_q    = (const float*)d_in[13];
  const float* a1_qdw  = (const float*)d_in[14];
  const float* a1_kv   = (const float*)d_in[15];
  const float* a1_kvdw = (const float*)d_in[16];
  const float* a1_po   = (const float*)d_in[17];
  const float* f1_in   = (const float*)d_in[18];
  const float* f1_dw   = (const float*)d_in[19];
  const float* f1_out  = (const float*)d_in[20];
  const float* a2_temp = (const float*)d_in[21];
  const float* a2_q    = (const float*)d_in[22];
  const float* a2_qdw  = (const float*)d_in[23];
  const float* a2_kv   = (const float*)d_in[24];
  const float* a2_kvdw = (const float*)d_in[25];
  const float* a2_po   = (const float*)d_in[26];
  const float* f2_in   = (const float*)d_in[27];
  const float* f2_dw   = (const float*)d_in[28];
  const float* f2_out  = (const float*)d_in[29];

  float* out = (float*)d_out;
  float* ws  = (float*)d_ws;

  // Choose the largest batch chunk NB whose workspace footprint fits ws_size.
  // footprint(NB) = 6 regions * (NB*288*4096) floats + small attn buffers.
  int NB = 16;
  while (NB > 1) {
    size_t U = (size_t)NB * 288 * HWS;
    size_t smallf = (size_t)NB * (82944 + 10368 + 288 + 288);
    size_t need = (6 * U + smallf) * sizeof(float);
    if (need <= ws_size) break;
    NB >>= 1;
  }
  size_t U = (size_t)NB * 288 * HWS;

  // branch 1: C=96, c=12
  for (int b0 = 0; b0 < BATCH; b0 += NB) {
    run_branch<12>(q_L + (size_t)b0 * 96 * HWS, fuse_L + (size_t)b0 * 96 * HWS,
                   n1_w, n1_b, n2_w, n2_b, a1_temp,
                   a1_q, a1_qdw, a1_kv, a1_kvdw, a1_po,
                   f1_in, f1_dw, f1_out,
                   out + (size_t)b0 * 96 * HWS, ws, U, NB, stream);
  }
  // branch 2: D=288, c=36 (q_H / fuse_H are contiguous [B,288,64,64] views)
  float* out2 = out + (size_t)BATCH * 96 * HWS;
  for (int b0 = 0; b0 < BATCH; b0 += NB) {
    run_branch<36>(q_H + (size_t)b0 * 288 * HWS, fuse_H + (size_t)b0 * 288 * HWS,
                   n3_w, n3_b, n4_w, n4_b, a2_temp,
                   a2_q, a2_qdw, a2_kv, a2_kvdw, a2_po,
                   f2_in, f2_dw, f2_out,
                   out2 + (size_t)b0 * 288 * HWS, ws, U, NB, stream);
  }
}

// Round 3
// 2802.333 us; speedup vs baseline: 1.2797x; 1.2797x over previous
//
#include <hip/hip_runtime.h>
#include <math.h>

#define HWS 4096
#define BATCH 16
#define WDIM 64

typedef _Float16 half8 __attribute__((ext_vector_type(8)));
typedef _Float16 half4 __attribute__((ext_vector_type(4)));
typedef _Float16 half2v __attribute__((ext_vector_type(2)));
typedef float floatx4 __attribute__((ext_vector_type(4)));

// ---------------- weight fp32 -> fp16 ----------------
__global__ void wcvt_kernel(const float* __restrict__ src, _Float16* __restrict__ dst, int n) {
  int i = blockIdx.x * 256 + threadIdx.x;
  if (i < n) dst[i] = (_Float16)src[i];
}

// ---------------- LayerNorm over channel dim -> f16 [p][c] ----------------
__global__ void ln16_kernel(const float* __restrict__ x, const float* __restrict__ w,
                            const float* __restrict__ bia, _Float16* __restrict__ out, int CH) {
  int b = blockIdx.y;
  int p = blockIdx.x * blockDim.x + threadIdx.x;
  const float* xp = x + (size_t)b * CH * HWS + p;
  float s = 0.f, s2 = 0.f;
  for (int c = 0; c < CH; ++c) { float v = xp[(size_t)c * HWS]; s += v; s2 = fmaf(v, v, s2); }
  float mu = s / CH;
  float var = s2 / CH - mu * mu;
  float inv = rsqrtf(var + 1e-5f);
  _Float16* op = out + ((size_t)b * HWS + p) * CH;
  for (int c = 0; c < CH; c += 4) {
    half4 hv;
    #pragma unroll
    for (int j = 0; j < 4; ++j) {
      float v = (xp[(size_t)(c + j) * HWS] - mu) * inv * w[c + j] + bia[c + j];
      hv[j] = (_Float16)v;
    }
    *reinterpret_cast<half4*>(&op[c]) = hv;
  }
}

// ---------------- fp32 [c][p] -> f16 [p][c] convert ----------------
__global__ void xcvt16_kernel(const float* __restrict__ x, _Float16* __restrict__ out, int CH) {
  int b = blockIdx.y;
  int p = blockIdx.x * blockDim.x + threadIdx.x;
  const float* xp = x + (size_t)b * CH * HWS + p;
  _Float16* op = out + ((size_t)b * HWS + p) * CH;
  for (int c = 0; c < CH; c += 4) {
    half4 hv;
    #pragma unroll
    for (int j = 0; j < 4; ++j) hv[j] = (_Float16)xp[(size_t)(c + j) * HWS];
    *reinterpret_cast<half4*>(&op[c]) = hv;
  }
}

// ---------------- conv1x1 via MFMA f16: out[b,o,p] = sum_k W[o,k] X[b,p,k] ----------------
// X16: [b][p][k] f16, W16: [o][k] f16, out: [b][o][p] f32 (+residual)
// grid (4096/256, O/96, NB), block 256 (4 waves). Tile 96(O) x 256(p).
template<bool RES>
__launch_bounds__(256)
__global__ void conv1x1_mfma(const _Float16* __restrict__ X16, const _Float16* __restrict__ W16,
                             const float* __restrict__ res, float* __restrict__ out,
                             int I, int O) {
  __shared__ _Float16 Xs[256 * 56];
  int b = blockIdx.z;
  int o0 = blockIdx.y * 96;
  int p0 = blockIdx.x * 256;
  int tid = threadIdx.x;
  int lane = tid & 63;
  int wn0 = (tid >> 6) * 64;   // wave's pixel slice
  int l15 = lane & 15, kg = lane >> 4;
  const _Float16* Xb = X16 + ((size_t)b * HWS + p0) * I;
  floatx4 acc[6][4] = {};
  int spl = tid >> 2, skc = (tid & 3) * 8;
  for (int k0 = 0; k0 < I; k0 += 32) {
    #pragma unroll
    for (int it = 0; it < 4; ++it) {
      half8 v = *reinterpret_cast<const half8*>(&Xb[(size_t)(spl + it * 64) * I + k0 + skc]);
      *reinterpret_cast<half8*>(&Xs[(spl + it * 64) * 56 + skc]) = v;
    }
    __syncthreads();
    half8 af[6], bf[4];
    #pragma unroll
    for (int mi = 0; mi < 6; ++mi)
      af[mi] = *reinterpret_cast<const half8*>(&W16[(size_t)(o0 + mi * 16 + l15) * I + k0 + kg * 8]);
    #pragma unroll
    for (int ni = 0; ni < 4; ++ni)
      bf[ni] = *reinterpret_cast<const half8*>(&Xs[(wn0 + ni * 16 + l15) * 56 + kg * 8]);
    #pragma unroll
    for (int mi = 0; mi < 6; ++mi)
      #pragma unroll
      for (int ni = 0; ni < 4; ++ni)
        acc[mi][ni] = __builtin_amdgcn_mfma_f32_16x16x32_f16(af[mi], bf[ni], acc[mi][ni], 0, 0, 0);
    __syncthreads();
  }
  int r4 = kg * 4;
  #pragma unroll
  for (int mi = 0; mi < 6; ++mi) {
    #pragma unroll
    for (int v = 0; v < 4; ++v) {
      int o = o0 + mi * 16 + r4 + v;
      size_t rowb = ((size_t)b * O + o) * HWS + p0;
      #pragma unroll
      for (int ni = 0; ni < 4; ++ni) {
        int p = wn0 + ni * 16 + l15;
        float val = acc[mi][ni][v];
        if (RES) val += res[rowb + p];
        out[rowb + p] = val;
      }
    }
  }
}

// ---------------- depthwise 3x3, zero pad (fp32) ----------------
__global__ void dw3_kernel(const float* __restrict__ in, const float* __restrict__ w,
                           float* __restrict__ out, int CH) {
  int bc = blockIdx.y;
  int ch = bc % CH;
  int p = blockIdx.x * blockDim.x + threadIdx.x;
  int y = p >> 6, x = p & 63;
  const float* ip = in + (size_t)bc * HWS;
  const float* wp = w + ch * 9;
  float s = 0.f;
  #pragma unroll
  for (int ky = 0; ky < 3; ++ky) {
    int yy = y + ky - 1;
    if (yy < 0 || yy >= WDIM) continue;
    #pragma unroll
    for (int kx = 0; kx < 3; ++kx) {
      int xx = x + kx - 1;
      if (xx < 0 || xx >= WDIM) continue;
      s = fmaf(wp[ky * 3 + kx], ip[yy * WDIM + xx], s);
    }
  }
  out[(size_t)bc * HWS + p] = s;
}

// ---------------- row L2 norm over HW (per b,channel) ----------------
__global__ void rownorm_kernel(const float* __restrict__ src, float* __restrict__ dst,
                               int CH, int ROWMUL) {
  int bc = blockIdx.x;
  int b = bc / CH, ch = bc % CH;
  const float* p = src + ((size_t)b * ROWMUL + ch) * HWS;
  float s = 0.f;
  for (int i = threadIdx.x; i < HWS; i += 256) { float v = p[i]; s = fmaf(v, v, s); }
  #pragma unroll
  for (int off = 32; off > 0; off >>= 1) s += __shfl_down(s, off, 64);
  __shared__ float red[4];
  int lane = threadIdx.x & 63, wv = threadIdx.x >> 6;
  if (lane == 0) red[wv] = s;
  __syncthreads();
  if (threadIdx.x == 0) {
    float t = red[0] + red[1] + red[2] + red[3];
    dst[bc] = fmaxf(sqrtf(t), 1e-12f);
  }
}

// ---------------- QK^T split-K partials ----------------
template<int c>
__global__ void qk_partial_kernel(const float* __restrict__ qb, const float* __restrict__ kvb,
                                  float* __restrict__ part, int CH) {
  constexpr int TC = c / 4;
  int split = blockIdx.x, bh = blockIdx.y;
  int b = bh >> 3, h = bh & 7;
  const float* qrow = qb + ((size_t)b * CH + h * c) * HWS;
  const float* krow = kvb + ((size_t)b * 2 * CH + h * c) * HWS;
  __shared__ float qs[c][65];
  __shared__ float ks[c][65];
  int tid = threadIdx.x;
  int tc = tid / TC, td = tid % TC;
  bool active = tid < TC * TC;
  float acc[4][4] = {};
  for (int s = 0; s < 8; ++s) {
    int n0 = split * 512 + s * 64;
    for (int e = tid; e < c * 64; e += 128) {
      int r = e >> 6, col = e & 63;
      qs[r][col] = qrow[(size_t)r * HWS + n0 + col];
      ks[r][col] = krow[(size_t)r * HWS + n0 + col];
    }
    __syncthreads();
    if (active) {
      for (int kk = 0; kk < 64; ++kk) {
        float a[4], bb[4];
        #pragma unroll
        for (int i = 0; i < 4; ++i) { a[i] = qs[tc * 4 + i][kk]; bb[i] = ks[td * 4 + i][kk]; }
        #pragma unroll
        for (int i = 0; i < 4; ++i)
          #pragma unroll
          for (int j = 0; j < 4; ++j)
            acc[i][j] = fmaf(a[i], bb[j], acc[i][j]);
      }
    }
    __syncthreads();
  }
  if (active) {
    #pragma unroll
    for (int i = 0; i < 4; ++i)
      #pragma unroll
      for (int j = 0; j < 4; ++j)
        part[(((size_t)bh * 8 + split) * 36 + tc * 4 + i) * 36 + td * 4 + j] = acc[i][j];
  }
}

// ---------------- reduce partials, norms+temp, softmax ----------------
template<int c>
__global__ void attn_softmax_kernel(const float* __restrict__ part, const float* __restrict__ nq,
                                    const float* __restrict__ nk, const float* __restrict__ temp,
                                    float* __restrict__ attnw, int CH) {
  int bh = blockIdx.x;
  int b = bh >> 3, h = bh & 7;
  __shared__ float Ss[c][c];
  int tid = threadIdx.x;
  for (int e = tid; e < c * c; e += 64) {
    int r = e / c, d = e % c;
    float s = 0.f;
    for (int sp = 0; sp < 8; ++sp)
      s += part[(((size_t)bh * 8 + sp) * 36 + r) * 36 + d];
    s = s / (nq[b * CH + h * c + r] * nk[b * CH + h * c + d]) * temp[h];
    Ss[r][d] = s;
  }
  __syncthreads();
  if (tid < c) {
    int r = tid;
    float m = -1e30f;
    for (int d = 0; d < c; ++d) m = fmaxf(m, Ss[r][d]);
    float sum = 0.f;
    for (int d = 0; d < c; ++d) { float e = expf(Ss[r][d] - m); sum += e; Ss[r][d] = e; }
    float inv = 1.f / sum;
    for (int d = 0; d < c; ++d)
      attnw[((size_t)bh * 36 + r) * 36 + d] = Ss[r][d] * inv;
  }
}

// ---------------- PV -> f16 [p][c] output ----------------
template<int c>
__global__ void pv_kernel(const float* __restrict__ attnw, const float* __restrict__ kvb,
                          _Float16* __restrict__ out, int CH) {
  __shared__ float As[c * c];
  int p = blockIdx.x * blockDim.x + threadIdx.x;
  int h = blockIdx.y, b = blockIdx.z;
  int bh = b * 8 + h;
  for (int e = threadIdx.x; e < c * c; e += 256)
    As[e] = attnw[((size_t)bh * 36 + e / c) * 36 + e % c];
  __syncthreads();
  const float* vb = kvb + ((size_t)b * 2 * CH + CH + h * c) * HWS + p;
  float vr[c];
  #pragma unroll
  for (int d = 0; d < c; ++d) vr[d] = vb[(size_t)d * HWS];
  _Float16* ob = out + ((size_t)b * HWS + p) * CH + h * c;
  #pragma unroll
  for (int ci = 0; ci < c; ci += 2) {
    float s0 = 0.f, s1 = 0.f;
    #pragma unroll
    for (int d = 0; d < c; ++d) {
      s0 = fmaf(As[ci * c + d], vr[d], s0);
      s1 = fmaf(As[(ci + 1) * c + d], vr[d], s1);
    }
    half2v hv; hv[0] = (_Float16)s0; hv[1] = (_Float16)s1;
    *reinterpret_cast<half2v*>(&ob[ci]) = hv;
  }
}

// ---------------- fused dwconv3+GELU gate -> f16 [p][c] ----------------
// in: f32 [b][2*C2][p]; out: f16 [b][p][C2]. grid (16, C2/32, NB), block 256.
__global__ void dwgate16_kernel(const float* __restrict__ in, const float* __restrict__ w,
                                _Float16* __restrict__ out, int C2) {
  int b = blockIdx.z;
  int ch0 = blockIdx.y * 32;
  int p = blockIdx.x * 256 + threadIdx.x;
  int y = p >> 6, x = p & 63;
  const float* base = in + (size_t)b * 2 * C2 * HWS;
  _Float16* ob = out + ((size_t)b * HWS + p) * C2 + ch0;
  for (int c8 = 0; c8 < 32; c8 += 8) {
    half8 hv;
    #pragma unroll
    for (int chl = 0; chl < 8; ++chl) {
      int ch = ch0 + c8 + chl;
      const float* i1 = base + (size_t)ch * HWS;
      const float* i2 = base + (size_t)(ch + C2) * HWS;
      const float* w1 = w + ch * 9;
      const float* w2 = w + (ch + C2) * 9;
      float s1 = 0.f, s2 = 0.f;
      #pragma unroll
      for (int ky = 0; ky < 3; ++ky) {
        int yy = y + ky - 1;
        if (yy < 0 || yy >= WDIM) continue;
        #pragma unroll
        for (int kx = 0; kx < 3; ++kx) {
          int xx = x + kx - 1;
          if (xx < 0 || xx >= WDIM) continue;
          s1 = fmaf(w1[ky * 3 + kx], i1[yy * WDIM + xx], s1);
          s2 = fmaf(w2[ky * 3 + kx], i2[yy * WDIM + xx], s2);
        }
      }
      float g = 0.5f * s1 * (1.f + erff(s1 * 0.70710678118654752f));
      hv[chl] = (_Float16)(g * s2);
    }
    *reinterpret_cast<half8*>(&ob[c8]) = hv;
  }
}

// ---------------- one transformer branch, one batch chunk of NB images ----------------
// Regions (U floats each, U sized for CH=288):
// attn: U0=ln16, U1=conv_q(f32), U2=dw_q, U5=fmap16, U3..U4=conv_kv, U0..U1=dw_kv,
//       U3=pv16, conv_po(+res)->xout
// ffn:  U5=ln16, U0..U3=conv_in(f32), U4=gate16, conv_out(+res)->xout
template<int c>
static void run_branch(const float* xin, const float* fmap,
                       const float* n1w, const float* n1b, const float* n2w, const float* n2b,
                       const float* temp, const _Float16* qw16, const float* qdw,
                       const _Float16* kvw16, const float* kvdw, const _Float16* pw16,
                       const _Float16* finw16, const float* fdw, const _Float16* foutw16,
                       float* xout, float* ws, size_t U, int NB, hipStream_t stream) {
  const int CH = 8 * c;
  float* U0 = ws;
  float* U1 = ws + U;
  float* U2 = ws + 2 * U;
  float* U3 = ws + 3 * U;
  float* U4 = ws + 4 * U;
  float* U5 = ws + 5 * U;
  float* part  = ws + 6 * U;
  float* attnw = part + (size_t)NB * 82944;
  float* nq    = attnw + (size_t)NB * 10368;
  float* nk    = nq + (size_t)NB * 288;

  dim3 blk(256);
  // ---- attention block ----
  ln16_kernel<<<dim3(16, NB), blk, 0, stream>>>(xin, n1w, n1b, (_Float16*)U0, CH);
  conv1x1_mfma<false><<<dim3(16, CH / 96, NB), blk, 0, stream>>>((_Float16*)U0, qw16, nullptr, U1, CH, CH);
  dw3_kernel<<<dim3(16, NB * CH), blk, 0, stream>>>(U1, qdw, U2, CH);
  xcvt16_kernel<<<dim3(16, NB), blk, 0, stream>>>(fmap, (_Float16*)U5, CH);
  conv1x1_mfma<false><<<dim3(16, 2 * CH / 96, NB), blk, 0, stream>>>((_Float16*)U5, kvw16, nullptr, U3, CH, 2 * CH);
  dw3_kernel<<<dim3(16, NB * 2 * CH), blk, 0, stream>>>(U3, kvdw, U0, 2 * CH);
  rownorm_kernel<<<dim3(NB * CH), blk, 0, stream>>>(U2, nq, CH, CH);
  rownorm_kernel<<<dim3(NB * CH), blk, 0, stream>>>(U0, nk, CH, 2 * CH);
  qk_partial_kernel<c><<<dim3(8, NB * 8), dim3(128), 0, stream>>>(U2, U0, part, CH);
  attn_softmax_kernel<c><<<dim3(NB * 8), dim3(64), 0, stream>>>(part, nq, nk, temp, attnw, CH);
  pv_kernel<c><<<dim3(16, 8, NB), blk, 0, stream>>>(attnw, U0, (_Float16*)U3, CH);
  conv1x1_mfma<true><<<dim3(16, CH / 96, NB), blk, 0, stream>>>((_Float16*)U3, pw16, xin, xout, CH, CH);
  // ---- FFN block ----
  ln16_kernel<<<dim3(16, NB), blk, 0, stream>>>(xout, n2w, n2b, (_Float16*)U5, CH);
  conv1x1_mfma<false><<<dim3(16, 4 * CH / 96, NB), blk, 0, stream>>>((_Float16*)U5, finw16, nullptr, U0, CH, 4 * CH);
  dwgate16_kernel<<<dim3(16, 2 * CH / 32, NB), blk, 0, stream>>>(U0, fdw, (_Float16*)U4, 2 * CH);
  conv1x1_mfma<true><<<dim3(16, CH / 96, NB), blk, 0, stream>>>((_Float16*)U4, foutw16, xout, xout, 2 * CH, CH);
}

extern "C" void kernel_launch(void* const* d_in, const int* in_sizes, int n_in,
                              void* d_out, int out_size, void* d_ws, size_t ws_size,
                              hipStream_t stream) {
  const float* q_L    = (const float*)d_in[0];
  const float* q_H    = (const float*)d_in[1];
  const float* fuse_L = (const float*)d_in[2];
  const float* fuse_H = (const float*)d_in[3];
  const float* n1_w = (const float*)d_in[4];
  const float* n1_b = (const float*)d_in[5];
  const float* n2_w = (const float*)d_in[6];
  const float* n2_b = (const float*)d_in[7];
  const float* n3_w = (const float*)d_in[8];
  const float* n3_b = (const float*)d_in[9];
  const float* n4_w = (const float*)d_in[10];
  const float* n4_b = (const float*)d_in[11];
  const float* a1_temp = (const float*)d_in[12];
  const float* a1_q    = (const float*)d_in[13];
  const float* a1_qdw  = (const float*)d_in[14];
  const float* a1_kv   = (const float*)d_in[15];
  const float* a1_kvdw = (const float*)d_in[16];
  const float* a1_po   = (const float*)d_in[17];
  const float* f1_in   = (const float*)d_in[18];
  const float* f1_dw   = (const float*)d_in[19];
  const float* f1_out  = (const float*)d_in[20];
  const float* a2_temp = (const float*)d_in[21];
  const float* a2_q    = (const float*)d_in[22];
  const float* a2_qdw  = (const float*)d_in[23];
  const float* a2_kv   = (const float*)d_in[24];
  const float* a2_kvdw = (const float*)d_in[25];
  const float* a2_po   = (const float*)d_in[26];
  const float* f2_in   = (const float*)d_in[27];
  const float* f2_dw   = (const float*)d_in[28];
  const float* f2_out  = (const float*)d_in[29];

  float* out = (float*)d_out;
  float* ws  = (float*)d_ws;

  // choose largest batch chunk NB that fits: 6 U-regions + attn smalls + f16 weights
  const size_t W16TOT = 921600;  // f16 elements, all 10 matrices
  int NB = 16;
  while (NB > 1) {
    size_t U = (size_t)NB * 288 * HWS;
    size_t smallf = (size_t)NB * (82944 + 10368 + 288 + 288);
    size_t need = (6 * U + smallf) * sizeof(float) + W16TOT * sizeof(_Float16);
    if (need <= ws_size) break;
    NB >>= 1;
  }
  size_t U = (size_t)NB * 288 * HWS;
  size_t smallf = (size_t)NB * (82944 + 10368 + 288 + 288);
  _Float16* w16 = (_Float16*)(ws + 6 * U + smallf);

  // convert all conv1x1 weights to f16 once per call
  const float* wsrc[10] = {a1_q, a1_kv, a1_po, f1_in, f1_out, a2_q, a2_kv, a2_po, f2_in, f2_out};
  const int    wcnt[10] = {9216, 18432, 9216, 36864, 18432, 82944, 165888, 82944, 331776, 165888};
  _Float16* wptr[10];
  {
    size_t off = 0;
    for (int i = 0; i < 10; ++i) {
      wptr[i] = w16 + off;
      wcvt_kernel<<<dim3((wcnt[i] + 255) / 256), dim3(256), 0, stream>>>(wsrc[i], wptr[i], wcnt[i]);
      off += wcnt[i];
    }
  }

  // branch 1: C=96, c=12
  for (int b0 = 0; b0 < BATCH; b0 += NB) {
    run_branch<12>(q_L + (size_t)b0 * 96 * HWS, fuse_L + (size_t)b0 * 96 * HWS,
                   n1_w, n1_b, n2_w, n2_b, a1_temp,
                   wptr[0], a1_qdw, wptr[1], a1_kvdw, wptr[2],
                   wptr[3], f1_dw, wptr[4],
                   out + (size_t)b0 * 96 * HWS, ws, U, NB, stream);
  }
  // branch 2: D=288, c=36
  float* out2 = out + (size_t)BATCH * 96 * HWS;
  for (int b0 = 0; b0 < BATCH; b0 += NB) {
    run_branch<36>(q_H + (size_t)b0 * 288 * HWS, fuse_H + (size_t)b0 * 288 * HWS,
                   n3_w, n3_b, n4_w, n4_b, a2_temp,
                   wptr[5], a2_qdw, wptr[6], a2_kvdw, wptr[7],
                   wptr[8], f2_dw, wptr[9],
                   out2 + (size_t)b0 * 288 * HWS, ws, U, NB, stream);
  }
}

// Round 4
// 2721.488 us; speedup vs baseline: 1.3178x; 1.0297x over previous
//
#include <hip/hip_runtime.h>
#include <math.h>

#define HWS 4096
#define BATCH 16
#define WDIM 64

typedef _Float16 half8 __attribute__((ext_vector_type(8)));
typedef _Float16 half4 __attribute__((ext_vector_type(4)));
typedef float floatx4 __attribute__((ext_vector_type(4)));

// ---------------- weight fp32 -> fp16 ----------------
__global__ void wcvt_kernel(const float* __restrict__ src, _Float16* __restrict__ dst, int n) {
  int i = blockIdx.x * 256 + threadIdx.x;
  if (i < n) dst[i] = (_Float16)src[i];
}

__global__ void zero_kernel(float* __restrict__ p, int n) {
  int i = blockIdx.x * 256 + threadIdx.x;
  if (i < n) p[i] = 0.f;
}

__global__ void sqrtmax_kernel(float* __restrict__ p, int n) {
  int i = blockIdx.x * 256 + threadIdx.x;
  if (i < n) p[i] = fmaxf(sqrtf(p[i]), 1e-12f);
}

// ---------------- LayerNorm over channel dim -> f16 [p][c], coalesced writes ----------------
__global__ void ln16_kernel(const float* __restrict__ x, const float* __restrict__ w,
                            const float* __restrict__ bia, _Float16* __restrict__ out, int CH) {
  __shared__ _Float16 T[256][38];
  int b = blockIdx.y;
  int tid = threadIdx.x;
  int p = blockIdx.x * 256 + tid;
  const float* xp = x + (size_t)b * CH * HWS + p;
  float s = 0.f, s2 = 0.f;
  for (int c = 0; c < CH; ++c) { float v = xp[(size_t)c * HWS]; s += v; s2 = fmaf(v, v, s2); }
  float mu = s / CH;
  float var = s2 / CH - mu * mu;
  float inv = rsqrtf(var + 1e-5f);
  _Float16* ob = out + ((size_t)b * HWS + (size_t)blockIdx.x * 256) * CH;
  for (int c0 = 0; c0 < CH; c0 += 32) {
    #pragma unroll
    for (int c8 = 0; c8 < 32; c8 += 8) {
      half8 hv;
      #pragma unroll
      for (int j = 0; j < 8; ++j) {
        int c = c0 + c8 + j;
        float v = (xp[(size_t)c * HWS] - mu) * inv * w[c] + bia[c];
        hv[j] = (_Float16)v;
      }
      *reinterpret_cast<half8*>(&T[tid][c8]) = hv;
    }
    __syncthreads();
    #pragma unroll
    for (int it = 0; it < 4; ++it) {
      int f = it * 256 + tid;
      int px = f >> 2, co = (f & 3) * 8;
      half8 v = *reinterpret_cast<const half8*>(&T[px][co]);
      *reinterpret_cast<half8*>(&ob[(size_t)px * CH + c0 + co]) = v;
    }
    __syncthreads();
  }
}

// ---------------- fp32 [c][p] -> f16 [p][c], coalesced writes ----------------
__global__ void xcvt16_kernel(const float* __restrict__ x, _Float16* __restrict__ out, int CH) {
  __shared__ _Float16 T[256][38];
  int b = blockIdx.y;
  int tid = threadIdx.x;
  int p = blockIdx.x * 256 + tid;
  const float* xp = x + (size_t)b * CH * HWS + p;
  _Float16* ob = out + ((size_t)b * HWS + (size_t)blockIdx.x * 256) * CH;
  for (int c0 = 0; c0 < CH; c0 += 32) {
    #pragma unroll
    for (int c8 = 0; c8 < 32; c8 += 8) {
      half8 hv;
      #pragma unroll
      for (int j = 0; j < 8; ++j) hv[j] = (_Float16)xp[(size_t)(c0 + c8 + j) * HWS];
      *reinterpret_cast<half8*>(&T[tid][c8]) = hv;
    }
    __syncthreads();
    #pragma unroll
    for (int it = 0; it < 4; ++it) {
      int f = it * 256 + tid;
      int px = f >> 2, co = (f & 3) * 8;
      half8 v = *reinterpret_cast<const half8*>(&T[px][co]);
      *reinterpret_cast<half8*>(&ob[(size_t)px * CH + c0 + co]) = v;
    }
    __syncthreads();
  }
}

// ---------------- conv1x1 via MFMA f16 ----------------
// X16: [b][p][k] f16, W16: [o][k] f16, out: [b][o][p] f32 (+residual)
// grid (4096/256, O/96, NB), block 256 (4 waves). Tile 96(O) x 256(p).
template<bool RES>
__launch_bounds__(256)
__global__ void conv1x1_mfma(const _Float16* __restrict__ X16, const _Float16* __restrict__ W16,
                             const float* __restrict__ res, float* __restrict__ out,
                             int I, int O) {
  __shared__ _Float16 Xs[256 * 56];
  int b = blockIdx.z;
  int o0 = blockIdx.y * 96;
  int p0 = blockIdx.x * 256;
  int tid = threadIdx.x;
  int lane = tid & 63;
  int wn0 = (tid >> 6) * 64;
  int l15 = lane & 15, kg = lane >> 4;
  const _Float16* Xb = X16 + ((size_t)b * HWS + p0) * I;
  floatx4 acc[6][4] = {};
  int spl = tid >> 2, skc = (tid & 3) * 8;
  for (int k0 = 0; k0 < I; k0 += 32) {
    #pragma unroll
    for (int it = 0; it < 4; ++it) {
      half8 v = *reinterpret_cast<const half8*>(&Xb[(size_t)(spl + it * 64) * I + k0 + skc]);
      *reinterpret_cast<half8*>(&Xs[(spl + it * 64) * 56 + skc]) = v;
    }
    __syncthreads();
    half8 af[6], bf[4];
    #pragma unroll
    for (int mi = 0; mi < 6; ++mi)
      af[mi] = *reinterpret_cast<const half8*>(&W16[(size_t)(o0 + mi * 16 + l15) * I + k0 + kg * 8]);
    #pragma unroll
    for (int ni = 0; ni < 4; ++ni)
      bf[ni] = *reinterpret_cast<const half8*>(&Xs[(wn0 + ni * 16 + l15) * 56 + kg * 8]);
    #pragma unroll
    for (int mi = 0; mi < 6; ++mi)
      #pragma unroll
      for (int ni = 0; ni < 4; ++ni)
        acc[mi][ni] = __builtin_amdgcn_mfma_f32_16x16x32_f16(af[mi], bf[ni], acc[mi][ni], 0, 0, 0);
    __syncthreads();
  }
  int r4 = kg * 4;
  #pragma unroll
  for (int mi = 0; mi < 6; ++mi) {
    #pragma unroll
    for (int v = 0; v < 4; ++v) {
      int o = o0 + mi * 16 + r4 + v;
      size_t rowb = ((size_t)b * O + o) * HWS + p0;
      #pragma unroll
      for (int ni = 0; ni < 4; ++ni) {
        int p = wn0 + ni * 16 + l15;
        float val = acc[mi][ni][v];
        if (RES) val += res[rowb + p];
        out[rowb + p] = val;
      }
    }
  }
}

// ---------------- depthwise 3x3 + fused sum-of-squares accumulation ----------------
// sumsq: per (b, ch<normCH) running sum of out^2 (for L2 norms), atomically accumulated.
__global__ void dw3_kernel(const float* __restrict__ in, const float* __restrict__ w,
                           float* __restrict__ out, int CH,
                           float* __restrict__ sumsq, int normCH) {
  int bc = blockIdx.y;
  int b = bc / CH, ch = bc % CH;
  int p = blockIdx.x * blockDim.x + threadIdx.x;
  int y = p >> 6, x = p & 63;
  const float* ip = in + (size_t)bc * HWS;
  const float* wp = w + ch * 9;
  float s = 0.f;
  #pragma unroll
  for (int ky = 0; ky < 3; ++ky) {
    int yy = y + ky - 1;
    if (yy < 0 || yy >= WDIM) continue;
    #pragma unroll
    for (int kx = 0; kx < 3; ++kx) {
      int xx = x + kx - 1;
      if (xx < 0 || xx >= WDIM) continue;
      s = fmaf(wp[ky * 3 + kx], ip[yy * WDIM + xx], s);
    }
  }
  out[(size_t)bc * HWS + p] = s;
  // fused norm accumulation
  float v = (ch < normCH) ? s * s : 0.f;
  #pragma unroll
  for (int off = 32; off > 0; off >>= 1) v += __shfl_down(v, off, 64);
  __shared__ float red[4];
  int lane = threadIdx.x & 63, wv = threadIdx.x >> 6;
  if (lane == 0) red[wv] = v;
  __syncthreads();
  if (threadIdx.x == 0 && ch < normCH) {
    float t = red[0] + red[1] + red[2] + red[3];
    atomicAdd(&sumsq[b * normCH + ch], t);
  }
}

// ---------------- QK^T split-K partials ----------------
template<int c>
__global__ void qk_partial_kernel(const float* __restrict__ qb, const float* __restrict__ kvb,
                                  float* __restrict__ part, int CH) {
  constexpr int TC = c / 4;
  int split = blockIdx.x, bh = blockIdx.y;
  int b = bh >> 3, h = bh & 7;
  const float* qrow = qb + ((size_t)b * CH + h * c) * HWS;
  const float* krow = kvb + ((size_t)b * 2 * CH + h * c) * HWS;
  __shared__ float qs[c][65];
  __shared__ float ks[c][65];
  int tid = threadIdx.x;
  int tc = tid / TC, td = tid % TC;
  bool active = tid < TC * TC;
  float acc[4][4] = {};
  for (int s = 0; s < 8; ++s) {
    int n0 = split * 512 + s * 64;
    for (int e = tid; e < c * 64; e += 128) {
      int r = e >> 6, col = e & 63;
      qs[r][col] = qrow[(size_t)r * HWS + n0 + col];
      ks[r][col] = krow[(size_t)r * HWS + n0 + col];
    }
    __syncthreads();
    if (active) {
      for (int kk = 0; kk < 64; ++kk) {
        float a[4], bb[4];
        #pragma unroll
        for (int i = 0; i < 4; ++i) { a[i] = qs[tc * 4 + i][kk]; bb[i] = ks[td * 4 + i][kk]; }
        #pragma unroll
        for (int i = 0; i < 4; ++i)
          #pragma unroll
          for (int j = 0; j < 4; ++j)
            acc[i][j] = fmaf(a[i], bb[j], acc[i][j]);
      }
    }
    __syncthreads();
  }
  if (active) {
    #pragma unroll
    for (int i = 0; i < 4; ++i)
      #pragma unroll
      for (int j = 0; j < 4; ++j)
        part[(((size_t)bh * 8 + split) * 36 + tc * 4 + i) * 36 + td * 4 + j] = acc[i][j];
  }
}

// ---------------- reduce partials, norms+temp, softmax ----------------
template<int c>
__global__ void attn_softmax_kernel(const float* __restrict__ part, const float* __restrict__ nq,
                                    const float* __restrict__ nk, const float* __restrict__ temp,
                                    float* __restrict__ attnw, int CH) {
  int bh = blockIdx.x;
  int b = bh >> 3, h = bh & 7;
  __shared__ float Ss[c][c];
  int tid = threadIdx.x;
  for (int e = tid; e < c * c; e += 64) {
    int r = e / c, d = e % c;
    float s = 0.f;
    for (int sp = 0; sp < 8; ++sp)
      s += part[(((size_t)bh * 8 + sp) * 36 + r) * 36 + d];
    s = s / (nq[b * CH + h * c + r] * nk[b * CH + h * c + d]) * temp[h];
    Ss[r][d] = s;
  }
  __syncthreads();
  if (tid < c) {
    int r = tid;
    float m = -1e30f;
    for (int d = 0; d < c; ++d) m = fmaxf(m, Ss[r][d]);
    float sum = 0.f;
    for (int d = 0; d < c; ++d) { float e = expf(Ss[r][d] - m); sum += e; Ss[r][d] = e; }
    float inv = 1.f / sum;
    for (int d = 0; d < c; ++d)
      attnw[((size_t)bh * 36 + r) * 36 + d] = Ss[r][d] * inv;
  }
}

// ---------------- PV -> f16 [p][c] output, coalesced writes ----------------
template<int c>
__global__ void pv_kernel(const float* __restrict__ attnw, const float* __restrict__ kvb,
                          _Float16* __restrict__ out, int CH) {
  constexpr int CPAD = (c == 36) ? 38 : 14;
  constexpr int Q4 = c / 4;            // half4 segments per pixel row
  __shared__ float As[c * c];
  __shared__ _Float16 T[256][CPAD];
  int tid = threadIdx.x;
  int p = blockIdx.x * 256 + tid;
  int h = blockIdx.y, b = blockIdx.z;
  int bh = b * 8 + h;
  for (int e = tid; e < c * c; e += 256)
    As[e] = attnw[((size_t)bh * 36 + e / c) * 36 + e % c];
  __syncthreads();
  const float* vb = kvb + ((size_t)b * 2 * CH + CH + h * c) * HWS + p;
  float vr[c];
  #pragma unroll
  for (int d = 0; d < c; ++d) vr[d] = vb[(size_t)d * HWS];
  #pragma unroll
  for (int ci = 0; ci < c; ci += 4) {
    half4 hv;
    #pragma unroll
    for (int j = 0; j < 4; ++j) {
      float s = 0.f;
      #pragma unroll
      for (int d = 0; d < c; ++d) s = fmaf(As[(ci + j) * c + d], vr[d], s);
      hv[j] = (_Float16)s;
    }
    *reinterpret_cast<half4*>(&T[tid][ci]) = hv;
  }
  __syncthreads();
  _Float16* ob = out + ((size_t)b * HWS + (size_t)blockIdx.x * 256) * CH + h * c;
  #pragma unroll
  for (int it = 0; it < Q4; ++it) {
    int f = it * 256 + tid;
    int px = f / Q4, co = (f % Q4) * 4;
    half4 v = *reinterpret_cast<const half4*>(&T[px][co]);
    *reinterpret_cast<half4*>(&ob[(size_t)px * CH + co]) = v;
  }
}

// ---------------- fused dwconv3+GELU gate -> f16 [p][c], coalesced writes ----------------
// in: f32 [b][2*C2][p]; out: f16 [b][p][C2]. grid (16, C2/32, NB), block 256.
__global__ void dwgate16_kernel(const float* __restrict__ in, const float* __restrict__ w,
                                _Float16* __restrict__ out, int C2) {
  __shared__ _Float16 T[256][38];
  int b = blockIdx.z;
  int ch0 = blockIdx.y * 32;
  int tid = threadIdx.x;
  int p = blockIdx.x * 256 + tid;
  int y = p >> 6, x = p & 63;
  const float* base = in + (size_t)b * 2 * C2 * HWS;
  for (int c8 = 0; c8 < 32; c8 += 8) {
    half8 hv;
    #pragma unroll
    for (int chl = 0; chl < 8; ++chl) {
      int ch = ch0 + c8 + chl;
      const float* i1 = base + (size_t)ch * HWS;
      const float* i2 = base + (size_t)(ch + C2) * HWS;
      const float* w1 = w + ch * 9;
      const float* w2 = w + (ch + C2) * 9;
      float s1 = 0.f, s2 = 0.f;
      #pragma unroll
      for (int ky = 0; ky < 3; ++ky) {
        int yy = y + ky - 1;
        if (yy < 0 || yy >= WDIM) continue;
        #pragma unroll
        for (int kx = 0; kx < 3; ++kx) {
          int xx = x + kx - 1;
          if (xx < 0 || xx >= WDIM) continue;
          s1 = fmaf(w1[ky * 3 + kx], i1[yy * WDIM + xx], s1);
          s2 = fmaf(w2[ky * 3 + kx], i2[yy * WDIM + xx], s2);
        }
      }
      float g = 0.5f * s1 * (1.f + erff(s1 * 0.70710678118654752f));
      hv[chl] = (_Float16)(g * s2);
    }
    *reinterpret_cast<half8*>(&T[tid][c8]) = hv;
  }
  __syncthreads();
  _Float16* ob = out + ((size_t)b * HWS + (size_t)blockIdx.x * 256) * C2 + ch0;
  #pragma unroll
  for (int it = 0; it < 4; ++it) {
    int f = it * 256 + tid;
    int px = f >> 2, co = (f & 3) * 8;
    half8 v = *reinterpret_cast<const half8*>(&T[px][co]);
    *reinterpret_cast<half8*>(&ob[(size_t)px * C2 + co]) = v;
  }
}

// ---------------- one transformer branch, one batch chunk of NB images ----------------
template<int c>
static void run_branch(const float* xin, const float* fmap,
                       const float* n1w, const float* n1b, const float* n2w, const float* n2b,
                       const float* temp, const _Float16* qw16, const float* qdw,
                       const _Float16* kvw16, const float* kvdw, const _Float16* pw16,
                       const _Float16* finw16, const float* fdw, const _Float16* foutw16,
                       float* xout, float* ws, size_t U, int NB, hipStream_t stream) {
  const int CH = 8 * c;
  float* U0 = ws;
  float* U1 = ws + U;
  float* U2 = ws + 2 * U;
  float* U3 = ws + 3 * U;
  float* U4 = ws + 4 * U;
  float* U5 = ws + 5 * U;
  float* part  = ws + 6 * U;
  float* attnw = part + (size_t)NB * 82944;
  float* nq    = attnw + (size_t)NB * 10368;
  float* nk    = nq + (size_t)NB * 288;

  dim3 blk(256);
  int nrm = 2 * NB * 288;
  // ---- attention block ----
  ln16_kernel<<<dim3(16, NB), blk, 0, stream>>>(xin, n1w, n1b, (_Float16*)U0, CH);
  zero_kernel<<<dim3((nrm + 255) / 256), blk, 0, stream>>>(nq, nrm);
  conv1x1_mfma<false><<<dim3(16, CH / 96, NB), blk, 0, stream>>>((_Float16*)U0, qw16, nullptr, U1, CH, CH);
  dw3_kernel<<<dim3(16, NB * CH), blk, 0, stream>>>(U1, qdw, U2, CH, nq, CH);
  xcvt16_kernel<<<dim3(16, NB), blk, 0, stream>>>(fmap, (_Float16*)U5, CH);
  conv1x1_mfma<false><<<dim3(16, 2 * CH / 96, NB), blk, 0, stream>>>((_Float16*)U5, kvw16, nullptr, U3, CH, 2 * CH);
  dw3_kernel<<<dim3(16, NB * 2 * CH), blk, 0, stream>>>(U3, kvdw, U0, 2 * CH, nk, CH);
  sqrtmax_kernel<<<dim3((nrm + 255) / 256), blk, 0, stream>>>(nq, nrm);
  qk_partial_kernel<c><<<dim3(8, NB * 8), dim3(128), 0, stream>>>(U2, U0, part, CH);
  attn_softmax_kernel<c><<<dim3(NB * 8), dim3(64), 0, stream>>>(part, nq, nk, temp, attnw, CH);
  pv_kernel<c><<<dim3(16, 8, NB), blk, 0, stream>>>(attnw, U0, (_Float16*)U3, CH);
  conv1x1_mfma<true><<<dim3(16, CH / 96, NB), blk, 0, stream>>>((_Float16*)U3, pw16, xin, xout, CH, CH);
  // ---- FFN block ----
  ln16_kernel<<<dim3(16, NB), blk, 0, stream>>>(xout, n2w, n2b, (_Float16*)U5, CH);
  conv1x1_mfma<false><<<dim3(16, 4 * CH / 96, NB), blk, 0, stream>>>((_Float16*)U5, finw16, nullptr, U0, CH, 4 * CH);
  dwgate16_kernel<<<dim3(16, 2 * CH / 32, NB), blk, 0, stream>>>(U0, fdw, (_Float16*)U4, 2 * CH);
  conv1x1_mfma<true><<<dim3(16, CH / 96, NB), blk, 0, stream>>>((_Float16*)U4, foutw16, xout, xout, 2 * CH, CH);
}

extern "C" void kernel_launch(void* const* d_in, const int* in_sizes, int n_in,
                              void* d_out, int out_size, void* d_ws, size_t ws_size,
                              hipStream_t stream) {
  const float* q_L    = (const float*)d_in[0];
  const float* q_H    = (const float*)d_in[1];
  const float* fuse_L = (const float*)d_in[2];
  const float* fuse_H = (const float*)d_in[3];
  const float* n1_w = (const float*)d_in[4];
  const float* n1_b = (const float*)d_in[5];
  const float* n2_w = (const float*)d_in[6];
  const float* n2_b = (const float*)d_in[7];
  const float* n3_w = (const float*)d_in[8];
  const float* n3_b = (const float*)d_in[9];
  const float* n4_w = (const float*)d_in[10];
  const float* n4_b = (const float*)d_in[11];
  const float* a1_temp = (const float*)d_in[12];
  const float* a1_q    = (const float*)d_in[13];
  const float* a1_qdw  = (const float*)d_in[14];
  const float* a1_kv   = (const float*)d_in[15];
  const float* a1_kvdw = (const float*)d_in[16];
  const float* a1_po   = (const float*)d_in[17];
  const float* f1_in   = (const float*)d_in[18];
  const float* f1_dw   = (const float*)d_in[19];
  const float* f1_out  = (const float*)d_in[20];
  const float* a2_temp = (const float*)d_in[21];
  const float* a2_q    = (const float*)d_in[22];
  const float* a2_qdw  = (const float*)d_in[23];
  const float* a2_kv   = (const float*)d_in[24];
  const float* a2_kvdw = (const float*)d_in[25];
  const float* a2_po   = (const float*)d_in[26];
  const float* f2_in   = (const float*)d_in[27];
  const float* f2_dw   = (const float*)d_in[28];
  const float* f2_out  = (const float*)d_in[29];

  float* out = (float*)d_out;
  float* ws  = (float*)d_ws;

  // choose largest batch chunk NB that fits: 6 U-regions + attn smalls + f16 weights
  const size_t W16TOT = 921600;  // f16 elements, all 10 matrices
  int NB = 16;
  while (NB > 1) {
    size_t U = (size_t)NB * 288 * HWS;
    size_t smallf = (size_t)NB * (82944 + 10368 + 288 + 288);
    size_t need = (6 * U + smallf) * sizeof(float) + W16TOT * sizeof(_Float16);
    if (need <= ws_size) break;
    NB >>= 1;
  }
  size_t U = (size_t)NB * 288 * HWS;
  size_t smallf = (size_t)NB * (82944 + 10368 + 288 + 288);
  _Float16* w16 = (_Float16*)(ws + 6 * U + smallf);

  // convert all conv1x1 weights to f16 once per call
  const float* wsrc[10] = {a1_q, a1_kv, a1_po, f1_in, f1_out, a2_q, a2_kv, a2_po, f2_in, f2_out};
  const int    wcnt[10] = {9216, 18432, 9216, 36864, 18432, 82944, 165888, 82944, 331776, 165888};
  _Float16* wptr[10];
  {
    size_t off = 0;
    for (int i = 0; i < 10; ++i) {
      wptr[i] = w16 + off;
      wcvt_kernel<<<dim3((wcnt[i] + 255) / 256), dim3(256), 0, stream>>>(wsrc[i], wptr[i], wcnt[i]);
      off += wcnt[i];
    }
  }

  // branch 1: C=96, c=12
  for (int b0 = 0; b0 < BATCH; b0 += NB) {
    run_branch<12>(q_L + (size_t)b0 * 96 * HWS, fuse_L + (size_t)b0 * 96 * HWS,
                   n1_w, n1_b, n2_w, n2_b, a1_temp,
                   wptr[0], a1_qdw, wptr[1], a1_kvdw, wptr[2],
                   wptr[3], f1_dw, wptr[4],
                   out + (size_t)b0 * 96 * HWS, ws, U, NB, stream);
  }
  // branch 2: D=288, c=36
  float* out2 = out + (size_t)BATCH * 96 * HWS;
  for (int b0 = 0; b0 < BATCH; b0 += NB) {
    run_branch<36>(q_H + (size_t)b0 * 288 * HWS, fuse_H + (size_t)b0 * 288 * HWS,
                   n3_w, n3_b, n4_w, n4_b, a2_temp,
                   wptr[5], a2_qdw, wptr[6], a2_kvdw, wptr[7],
                   wptr[8], f2_dw, wptr[9],
                   out2 + (size_t)b0 * 288 * HWS, ws, U, NB, stream);
  }
}